// Round 1
// baseline (908.168 us; speedup 1.0000x reference)
//
#include <hip/hip_runtime.h>

#define T_TOK 2048
#define HDIM  1024
#define FDIM  512
#define NEXP  64
#define TOPK  8
#define NGRP  8
#define TGRP  4
#define CAPC  1024
#define SCALE_F 2.5f

typedef _Float16 f16;
typedef _Float16 f16x4 __attribute__((ext_vector_type(4)));
typedef _Float16 f16x8 __attribute__((ext_vector_type(8)));
typedef float    f32x4 __attribute__((ext_vector_type(4)));

// ---------------------------------------------------------------------------
// Routing: one wave per token. fp32 logits, sigmoid, group-limited top-k.
// Also writes xb = fp16(x) and assigns slot positions via atomics.
// ---------------------------------------------------------------------------
__global__ void k_route(const float* __restrict__ x, const float* __restrict__ gw,
                        const float* __restrict__ ebias,
                        f16* __restrict__ xb,
                        int* __restrict__ counts,
                        int* __restrict__ slot_e, int* __restrict__ slot_pos,
                        float* __restrict__ slot_w)
{
    int t = blockIdx.x;
    int lane = threadIdx.x; // 64 threads = 1 wave
    __shared__ float4 sx[HDIM / 4];
    __shared__ float sS[NEXP], sF[NEXP];
    __shared__ float gsc[NGRP];
    __shared__ unsigned gmask_s;
    __shared__ int sIdx[TOPK];

    const float4* xr = (const float4*)(x + (size_t)t * HDIM);
    for (int i = lane; i < HDIM / 4; i += 64) sx[i] = xr[i];
    __syncthreads();

    // fp16 copy of the token (used by both expert paths)
    for (int i = lane; i < HDIM / 4; i += 64) {
        float4 v = sx[i];
        f16x4 h = { (f16)v.x, (f16)v.y, (f16)v.z, (f16)v.w };
        *(f16x4*)(xb + (size_t)t * HDIM + i * 4) = h;
    }

    // logits: lane e computes dot(x[t], gw[e])
    const float4* wr = (const float4*)(gw + (size_t)lane * HDIM);
    float acc = 0.f;
    #pragma unroll 8
    for (int i = 0; i < HDIM / 4; ++i) {
        float4 a = sx[i]; float4 b = wr[i];
        acc += a.x * b.x + a.y * b.y + a.z * b.z + a.w * b.w;
    }
    float score = 1.f / (1.f + __expf(-acc));
    float sfc = score + ebias[lane];
    sS[lane] = score; sF[lane] = sfc;
    __syncthreads();

    // per-group sum of top-2
    if (lane < NGRP) {
        float m1 = -1e30f, m2 = -1e30f;
        for (int j = 0; j < NEXP / NGRP; ++j) {
            float v = sF[lane * (NEXP / NGRP) + j];
            if (v > m1) { m2 = m1; m1 = v; } else if (v > m2) m2 = v;
        }
        gsc[lane] = m1 + m2;
    }
    __syncthreads();
    // top-TG groups (lane 0, ties -> lower index like jax.top_k)
    if (lane == 0) {
        unsigned gm = 0;
        for (int s = 0; s < TGRP; ++s) {
            float best = -1e30f; int bg = 0;
            for (int g = 0; g < NGRP; ++g)
                if (!((gm >> g) & 1) && gsc[g] > best) { best = gsc[g]; bg = g; }
            gm |= 1u << bg;
        }
        gmask_s = gm;
    }
    __syncthreads();

    float vv = ((gmask_s >> (lane >> 3)) & 1) ? sfc : 0.0f;  // masked candidates
    for (int k = 0; k < TOPK; ++k) {
        float bv = vv; int bi = lane;
        for (int off = 32; off; off >>= 1) {
            float ov = __shfl_down(bv, off);
            int   oi = __shfl_down(bi, off);
            if (ov > bv || (ov == bv && oi < bi)) { bv = ov; bi = oi; }
        }
        bi = __shfl(bi, 0);
        if (lane == bi) vv = -1e30f;
        if (lane == 0) sIdx[k] = bi;
    }
    __syncthreads();
    if (lane == 0) {
        float sum = 0.f;
        for (int k = 0; k < TOPK; ++k) sum += sS[sIdx[k]];
        float inv = SCALE_F / (sum + 1e-20f);
        for (int k = 0; k < TOPK; ++k) {
            int e = sIdx[k];
            int pos = atomicAdd(&counts[e], 1);
            int s = t * TOPK + k;
            slot_e[s] = e; slot_pos[s] = pos; slot_w[s] = sS[e] * inv;
        }
    }
}

__global__ void k_scan(const int* __restrict__ counts, int* __restrict__ offsets)
{
    if (threadIdx.x == 0) {
        int s = 0;
        for (int e = 0; e < NEXP; ++e) { offsets[e] = s; s += counts[e]; }
    }
}

__global__ void k_rowmap(const int* __restrict__ slot_e, const int* __restrict__ slot_pos,
                         const int* __restrict__ offsets, int* __restrict__ row_tok)
{
    int s = blockIdx.x * 256 + threadIdx.x;
    if (s >= T_TOK * TOPK) return;
    int p = slot_pos[s];
    if (p >= CAPC) return;
    row_tok[offsets[slot_e[s]] + p] = s >> 3;
}

// ---------------------------------------------------------------------------
// Fused gate-up GEMM: H = silu(A.W1^T) * (A.W3^T).  C-tile 128(M) x 64(N),
// 4 waves each 64x32 for BOTH outputs. W staged fp32->fp16 on the fly.
// expert_mode: A rows come through row_tok indirection; W gets e-offset.
// ---------------------------------------------------------------------------
__global__ __launch_bounds__(256, 2) void k_gateup(
    const f16* __restrict__ A, const float* __restrict__ W1,
    const float* __restrict__ W3, f16* __restrict__ Hout,
    const int* __restrict__ offsets, const int* __restrict__ counts,
    const int* __restrict__ row_tok,
    int K, int Nld, int Mtot, int expert_mode)
{
    int e = expert_mode ? blockIdx.z : 0;
    int rowbeg = expert_mode ? offsets[e] : 0;
    int M = expert_mode ? (counts[e] < CAPC ? counts[e] : CAPC) : Mtot;
    int mtile = blockIdx.y * 128;
    if (mtile >= M) return;
    int Mblk = M - mtile; if (Mblk > 128) Mblk = 128;
    int n0 = blockIdx.x * 64;
    const float* W1e = W1 + (size_t)e * Nld * K;
    const float* W3e = W3 + (size_t)e * Nld * K;

    __shared__ __align__(16) f16 sA[128][72];
    __shared__ __align__(16) f16 sB1[64][72];
    __shared__ __align__(16) f16 sB3[64][72];

    int tid = threadIdx.x;
    int wave = tid >> 6, lane = tid & 63;
    int wm = (wave & 1) * 64, wn = (wave >> 1) * 32;
    int lrow = lane & 15, lquad = lane >> 4;

    f32x4 accg[4][2], accu[4][2];
    #pragma unroll
    for (int i = 0; i < 4; ++i)
        #pragma unroll
        for (int j = 0; j < 2; ++j) {
            f32x4 z = {0.f, 0.f, 0.f, 0.f};
            accg[i][j] = z; accu[i][j] = z;
        }

    int ar = tid >> 3, aseg = tid & 7;
    const f16* arowp[4];
    #pragma unroll
    for (int it = 0; it < 4; ++it) {
        int r = ar + it * 32;
        int rr = (r < Mblk) ? r : 0;              // clamp: garbage rows never stored
        int grow = mtile + rr;
        size_t srow = expert_mode ? (size_t)row_tok[rowbeg + grow]
                                  : (size_t)(rowbeg + grow);
        arowp[it] = A + srow * (size_t)K + aseg * 8;
    }
    int wrow = tid >> 4, wseg = tid & 15;

    for (int k0 = 0; k0 < K; k0 += 64) {
        #pragma unroll
        for (int it = 0; it < 4; ++it) {
            uint4 v = *(const uint4*)(arowp[it] + k0);
            *(uint4*)&sA[ar + it * 32][aseg * 8] = v;
        }
        #pragma unroll
        for (int it = 0; it < 4; ++it) {
            int n = wrow + it * 16;
            float4 v1 = *(const float4*)(W1e + (size_t)(n0 + n) * K + k0 + wseg * 4);
            float4 v3 = *(const float4*)(W3e + (size_t)(n0 + n) * K + k0 + wseg * 4);
            f16x4 h1 = { (f16)v1.x, (f16)v1.y, (f16)v1.z, (f16)v1.w };
            f16x4 h3 = { (f16)v3.x, (f16)v3.y, (f16)v3.z, (f16)v3.w };
            *(f16x4*)&sB1[n][wseg * 4] = h1;
            *(f16x4*)&sB3[n][wseg * 4] = h3;
        }
        __syncthreads();
        #pragma unroll
        for (int ks = 0; ks < 64; ks += 32) {
            int kf = ks + lquad * 8;
            f16x8 a[4], b1[2], b3[2];
            #pragma unroll
            for (int i = 0; i < 4; ++i) a[i] = *(const f16x8*)&sA[wm + i * 16 + lrow][kf];
            #pragma unroll
            for (int j = 0; j < 2; ++j) {
                b1[j] = *(const f16x8*)&sB1[wn + j * 16 + lrow][kf];
                b3[j] = *(const f16x8*)&sB3[wn + j * 16 + lrow][kf];
            }
            #pragma unroll
            for (int i = 0; i < 4; ++i)
                #pragma unroll
                for (int j = 0; j < 2; ++j) {
                    accg[i][j] = __builtin_amdgcn_mfma_f32_16x16x32_f16(a[i], b1[j], accg[i][j], 0, 0, 0);
                    accu[i][j] = __builtin_amdgcn_mfma_f32_16x16x32_f16(a[i], b3[j], accu[i][j], 0, 0, 0);
                }
        }
        __syncthreads();
    }

    f16* Hrow = Hout + (size_t)(rowbeg + mtile) * Nld + n0;
    #pragma unroll
    for (int i = 0; i < 4; ++i)
        #pragma unroll
        for (int j = 0; j < 2; ++j)
            #pragma unroll
            for (int r = 0; r < 4; ++r) {
                int m = wm + i * 16 + lquad * 4 + r;
                if (m < Mblk) {
                    int n = wn + j * 16 + lrow;
                    float g = accg[i][j][r], u = accu[i][j][r];
                    float h = g / (1.f + __expf(-g)) * u;   // silu(g)*u
                    Hrow[(size_t)m * Nld + n] = (f16)h;
                }
            }
}

// ---------------------------------------------------------------------------
// Down GEMM: Y = A.W^T.  C-tile 128x128, 4 waves each 64x64.
// ---------------------------------------------------------------------------
__global__ __launch_bounds__(256, 2) void k_down(
    const f16* __restrict__ A, const float* __restrict__ W,
    f16* __restrict__ Y,
    const int* __restrict__ offsets, const int* __restrict__ counts,
    int K, int Nld, int Mtot, int expert_mode)
{
    int e = expert_mode ? blockIdx.z : 0;
    int rowbeg = expert_mode ? offsets[e] : 0;
    int M = expert_mode ? (counts[e] < CAPC ? counts[e] : CAPC) : Mtot;
    int mtile = blockIdx.y * 128;
    if (mtile >= M) return;
    int Mblk = M - mtile; if (Mblk > 128) Mblk = 128;
    int n0 = blockIdx.x * 128;
    const float* We = W + (size_t)e * Nld * K;

    __shared__ __align__(16) f16 sA[128][72];
    __shared__ __align__(16) f16 sW[128][72];

    int tid = threadIdx.x;
    int wave = tid >> 6, lane = tid & 63;
    int wm = (wave & 1) * 64, wn = (wave >> 1) * 64;
    int lrow = lane & 15, lquad = lane >> 4;

    f32x4 acc[4][4];
    #pragma unroll
    for (int i = 0; i < 4; ++i)
        #pragma unroll
        for (int j = 0; j < 4; ++j) { f32x4 z = {0.f, 0.f, 0.f, 0.f}; acc[i][j] = z; }

    int ar = tid >> 3, aseg = tid & 7;
    const f16* arowp[4];
    #pragma unroll
    for (int it = 0; it < 4; ++it) {
        int r = ar + it * 32;
        int rr = (r < Mblk) ? r : 0;
        arowp[it] = A + (size_t)(rowbeg + mtile + rr) * K + aseg * 8;
    }
    int wrow = tid >> 4, wseg = tid & 15;

    for (int k0 = 0; k0 < K; k0 += 64) {
        #pragma unroll
        for (int it = 0; it < 4; ++it) {
            uint4 v = *(const uint4*)(arowp[it] + k0);
            *(uint4*)&sA[ar + it * 32][aseg * 8] = v;
        }
        #pragma unroll
        for (int it = 0; it < 8; ++it) {
            int n = wrow + it * 16;
            float4 v = *(const float4*)(We + (size_t)(n0 + n) * K + k0 + wseg * 4);
            f16x4 h = { (f16)v.x, (f16)v.y, (f16)v.z, (f16)v.w };
            *(f16x4*)&sW[n][wseg * 4] = h;
        }
        __syncthreads();
        #pragma unroll
        for (int ks = 0; ks < 64; ks += 32) {
            int kf = ks + lquad * 8;
            f16x8 a[4], b[4];
            #pragma unroll
            for (int i = 0; i < 4; ++i) a[i] = *(const f16x8*)&sA[wm + i * 16 + lrow][kf];
            #pragma unroll
            for (int j = 0; j < 4; ++j) b[j] = *(const f16x8*)&sW[wn + j * 16 + lrow][kf];
            #pragma unroll
            for (int i = 0; i < 4; ++i)
                #pragma unroll
                for (int j = 0; j < 4; ++j)
                    acc[i][j] = __builtin_amdgcn_mfma_f32_16x16x32_f16(a[i], b[j], acc[i][j], 0, 0, 0);
        }
        __syncthreads();
    }

    f16* Yrow = Y + (size_t)(rowbeg + mtile) * Nld + n0;
    #pragma unroll
    for (int i = 0; i < 4; ++i)
        #pragma unroll
        for (int j = 0; j < 4; ++j)
            #pragma unroll
            for (int r = 0; r < 4; ++r) {
                int m = wm + i * 16 + lquad * 4 + r;
                if (m < Mblk)
                    Yrow[(size_t)m * Nld + wn + j * 16 + lrow] = (f16)acc[i][j][r];
            }
}

// ---------------------------------------------------------------------------
// Combine: out[t] = ys[t] + sum_k w_k * y[row(t,k)]   (fp32 output)
// ---------------------------------------------------------------------------
__global__ void k_combine(const f16* __restrict__ y, const f16* __restrict__ ys,
                          const int* __restrict__ slot_e, const int* __restrict__ slot_pos,
                          const float* __restrict__ slot_w, const int* __restrict__ offsets,
                          float* __restrict__ out)
{
    int t = blockIdx.x, i = threadIdx.x;   // 256 threads x 4 cols
    size_t col = (size_t)i * 4;
    f16x4 s = *(const f16x4*)(ys + (size_t)t * HDIM + col);
    float a0 = (float)s[0], a1 = (float)s[1], a2 = (float)s[2], a3 = (float)s[3];
    #pragma unroll
    for (int k = 0; k < TOPK; ++k) {
        int sidx = t * TOPK + k;
        int p = slot_pos[sidx];
        if (p < CAPC) {
            int row = offsets[slot_e[sidx]] + p;
            float w = slot_w[sidx];
            f16x4 v = *(const f16x4*)(y + (size_t)row * HDIM + col);
            a0 += w * (float)v[0]; a1 += w * (float)v[1];
            a2 += w * (float)v[2]; a3 += w * (float)v[3];
        }
    }
    float4 o = {a0, a1, a2, a3};
    *(float4*)(out + (size_t)t * HDIM + col) = o;
}

extern "C" void kernel_launch(void* const* d_in, const int* in_sizes, int n_in,
                              void* d_out, int out_size, void* d_ws, size_t ws_size,
                              hipStream_t stream)
{
    const float* x  = (const float*)d_in[0];
    const float* gw = (const float*)d_in[1];
    const float* eb = (const float*)d_in[2];
    const float* w1 = (const float*)d_in[3];
    const float* w2 = (const float*)d_in[4];
    const float* w3 = (const float*)d_in[5];
    const float* sg = (const float*)d_in[6];
    const float* su = (const float*)d_in[7];
    const float* sd = (const float*)d_in[8];
    float* out = (float*)d_out;

    char* p = (char*)d_ws;
    size_t off = 0;
    auto alloc = [&](size_t n) { void* r = p + off; off = (off + n + 255) & ~(size_t)255; return r; };
    int*   counts   = (int*)alloc(NEXP * 4);
    int*   offsets  = (int*)alloc(NEXP * 4);
    int*   slot_e   = (int*)alloc((size_t)T_TOK * TOPK * 4);
    int*   slot_pos = (int*)alloc((size_t)T_TOK * TOPK * 4);
    float* slot_w   = (float*)alloc((size_t)T_TOK * TOPK * 4);
    int*   row_tok  = (int*)alloc((size_t)T_TOK * TOPK * 4);
    f16*   xb = (f16*)alloc((size_t)T_TOK * HDIM * 2);          // 4 MB
    f16*   h  = (f16*)alloc((size_t)T_TOK * TOPK * FDIM * 2);   // 16 MB
    f16*   y  = (f16*)alloc((size_t)T_TOK * TOPK * HDIM * 2);   // 32 MB
    f16*   hs = (f16*)alloc((size_t)T_TOK * 2 * FDIM * 2);      // 4 MB
    f16*   ys = (f16*)alloc((size_t)T_TOK * HDIM * 2);          // 4 MB

    hipMemsetAsync(counts, 0, NEXP * 4, stream);
    k_route<<<T_TOK, 64, 0, stream>>>(x, gw, eb, xb, counts, slot_e, slot_pos, slot_w);
    k_scan<<<1, 64, 0, stream>>>(counts, offsets);
    k_rowmap<<<(T_TOK * TOPK + 255) / 256, 256, 0, stream>>>(slot_e, slot_pos, offsets, row_tok);

    // routed gate-up: h[rows,512] = silu(x.w1^T)*(x.w3^T)
    k_gateup<<<dim3(FDIM / 64, CAPC / 128, NEXP), 256, 0, stream>>>(
        xb, w1, w3, h, offsets, counts, row_tok, HDIM, FDIM, 0, 1);
    // shared gate-up: hs[2048,1024]
    k_gateup<<<dim3((2 * FDIM) / 64, T_TOK / 128, 1), 256, 0, stream>>>(
        xb, sg, su, hs, offsets, counts, row_tok, HDIM, 2 * FDIM, T_TOK, 0);
    // routed down: y[rows,1024] = h.w2^T
    k_down<<<dim3(HDIM / 128, CAPC / 128, NEXP), 256, 0, stream>>>(
        h, w2, y, offsets, counts, FDIM, HDIM, 0, 1);
    // shared down: ys[2048,1024] = hs.sd^T
    k_down<<<dim3(HDIM / 128, T_TOK / 128, 1), 256, 0, stream>>>(
        hs, sd, ys, offsets, counts, 2 * FDIM, HDIM, T_TOK, 0);

    k_combine<<<T_TOK, 256, 0, stream>>>(y, ys, slot_e, slot_pos, slot_w, offsets, out);
}

// Round 2
// 730.271 us; speedup vs baseline: 1.2436x; 1.2436x over previous
//
#include <hip/hip_runtime.h>

#define T_TOK 2048
#define HDIM  1024
#define FDIM  512
#define NEXP  64
#define TOPK  8
#define NGRP  8
#define TGRP  4
#define CAPC  1024
#define SCALE_F 2.5f

typedef _Float16 f16;
typedef _Float16 f16x4 __attribute__((ext_vector_type(4)));
typedef _Float16 f16x8 __attribute__((ext_vector_type(8)));
typedef float    f32x4 __attribute__((ext_vector_type(4)));

typedef const __attribute__((address_space(1))) void* gas_t;
typedef __attribute__((address_space(3))) void* las_t;
__device__ __forceinline__ void gl2lds16(const void* g, void* l) {
    __builtin_amdgcn_global_load_lds((gas_t)g, (las_t)l, 16, 0, 0);
}
// XOR-swizzled fragment read: logical (row r, 16B-seg s) -> phys seg s^(r&7)
#define FRAG(S, r, s) (*(const f16x8*)&S[(r)*64 + (((s) ^ ((r)&7)))*8])

// ---------------------------------------------------------------------------
// fp32 -> f16 streaming conversion (8 elems/thread)
// ---------------------------------------------------------------------------
__global__ void k_cvt(const float* __restrict__ src, f16* __restrict__ dst, int n8)
{
    int i = blockIdx.x * blockDim.x + threadIdx.x;
    if (i >= n8) return;
    const float4* s = (const float4*)src + (size_t)i * 2;
    float4 a = s[0], b = s[1];
    f16x8 h = { (f16)a.x, (f16)a.y, (f16)a.z, (f16)a.w,
                (f16)b.x, (f16)b.y, (f16)b.z, (f16)b.w };
    *(f16x8*)(dst + (size_t)i * 8) = h;
}

// ---------------------------------------------------------------------------
// Routing: one wave per token (fp32 throughout; also emits f16 copy of x)
// ---------------------------------------------------------------------------
__global__ void k_route(const float* __restrict__ x, const float* __restrict__ gw,
                        const float* __restrict__ ebias,
                        f16* __restrict__ xb,
                        int* __restrict__ counts,
                        int* __restrict__ slot_e, int* __restrict__ slot_pos,
                        float* __restrict__ slot_w)
{
    int t = blockIdx.x;
    int lane = threadIdx.x; // 64 threads = 1 wave
    __shared__ float4 sx[HDIM / 4];
    __shared__ float sS[NEXP], sF[NEXP];
    __shared__ float gsc[NGRP];
    __shared__ unsigned gmask_s;
    __shared__ int sIdx[TOPK];

    const float4* xr = (const float4*)(x + (size_t)t * HDIM);
    for (int i = lane; i < HDIM / 4; i += 64) sx[i] = xr[i];
    __syncthreads();

    for (int i = lane; i < HDIM / 4; i += 64) {
        float4 v = sx[i];
        f16x4 h = { (f16)v.x, (f16)v.y, (f16)v.z, (f16)v.w };
        *(f16x4*)(xb + (size_t)t * HDIM + i * 4) = h;
    }

    const float4* wr = (const float4*)(gw + (size_t)lane * HDIM);
    float acc = 0.f;
    #pragma unroll 8
    for (int i = 0; i < HDIM / 4; ++i) {
        float4 a = sx[i]; float4 b = wr[i];
        acc += a.x * b.x + a.y * b.y + a.z * b.z + a.w * b.w;
    }
    float score = 1.f / (1.f + __expf(-acc));
    float sfc = score + ebias[lane];
    sS[lane] = score; sF[lane] = sfc;
    __syncthreads();

    if (lane < NGRP) {
        float m1 = -1e30f, m2 = -1e30f;
        for (int j = 0; j < NEXP / NGRP; ++j) {
            float v = sF[lane * (NEXP / NGRP) + j];
            if (v > m1) { m2 = m1; m1 = v; } else if (v > m2) m2 = v;
        }
        gsc[lane] = m1 + m2;
    }
    __syncthreads();
    if (lane == 0) {
        unsigned gm = 0;
        for (int s = 0; s < TGRP; ++s) {
            float best = -1e30f; int bg = 0;
            for (int g = 0; g < NGRP; ++g)
                if (!((gm >> g) & 1) && gsc[g] > best) { best = gsc[g]; bg = g; }
            gm |= 1u << bg;
        }
        gmask_s = gm;
    }
    __syncthreads();

    float vv = ((gmask_s >> (lane >> 3)) & 1) ? sfc : 0.0f;
    for (int k = 0; k < TOPK; ++k) {
        float bv = vv; int bi = lane;
        for (int off = 32; off; off >>= 1) {
            float ov = __shfl_down(bv, off);
            int   oi = __shfl_down(bi, off);
            if (ov > bv || (ov == bv && oi < bi)) { bv = ov; bi = oi; }
        }
        bi = __shfl(bi, 0);
        if (lane == bi) vv = -1e30f;
        if (lane == 0) sIdx[k] = bi;
    }
    __syncthreads();
    if (lane == 0) {
        float sum = 0.f;
        for (int k = 0; k < TOPK; ++k) sum += sS[sIdx[k]];
        float inv = SCALE_F / (sum + 1e-20f);
        for (int k = 0; k < TOPK; ++k) {
            int e = sIdx[k];
            int pos = atomicAdd(&counts[e], 1);
            int s = t * TOPK + k;
            slot_e[s] = e; slot_pos[s] = pos; slot_w[s] = sS[e] * inv;
        }
    }
}

__global__ void k_scan(const int* __restrict__ counts, int* __restrict__ offsets)
{
    if (threadIdx.x == 0) {
        int s = 0;
        for (int e = 0; e < NEXP; ++e) { offsets[e] = s; s += counts[e]; }
    }
}

__global__ void k_rowmap(const int* __restrict__ slot_e, const int* __restrict__ slot_pos,
                         const int* __restrict__ offsets, int* __restrict__ row_tok)
{
    int s = blockIdx.x * 256 + threadIdx.x;
    if (s >= T_TOK * TOPK) return;
    int p = slot_pos[s];
    if (p >= CAPC) return;
    row_tok[offsets[slot_e[s]] + p] = s >> 3;
}

// ---------------------------------------------------------------------------
// Fused gate-up GEMM (all-f16): H = silu(A.W1^T) * (A.W3^T).
// Tile 128M x 64N; global_load_lds(16B) staging, XOR-swizzled LDS.
// ---------------------------------------------------------------------------
__global__ __launch_bounds__(256, 2) void k_gateup(
    const f16* __restrict__ A, const f16* __restrict__ W1,
    const f16* __restrict__ W3, f16* __restrict__ Hout,
    const int* __restrict__ offsets, const int* __restrict__ counts,
    const int* __restrict__ row_tok,
    int K, int Nld, int Mtot, int expert_mode)
{
    int e = expert_mode ? blockIdx.z : 0;
    int rowbeg = expert_mode ? offsets[e] : 0;
    int M = expert_mode ? (counts[e] < CAPC ? counts[e] : CAPC) : Mtot;
    int mtile = blockIdx.y * 128;
    if (mtile >= M) return;
    int Mblk = M - mtile; if (Mblk > 128) Mblk = 128;
    int n0 = blockIdx.x * 64;
    const f16* W1e = W1 + (size_t)e * Nld * K;
    const f16* W3e = W3 + (size_t)e * Nld * K;

    __shared__ __align__(16) f16 sA[128 * 64];
    __shared__ __align__(16) f16 sB1[64 * 64];
    __shared__ __align__(16) f16 sB3[64 * 64];

    int tid = threadIdx.x, wave = tid >> 6, lane = tid & 63;
    int subrow = lane >> 3;                       // 0..7 within staging chunk
    int lseg = (lane & 7) ^ subrow;               // swizzled source 16B-seg

    // A: 16 chunks of 8 rows; 4 per wave
    const f16* aptr[4];
    #pragma unroll
    for (int c = 0; c < 4; ++c) {
        int r = (wave * 4 + c) * 8 + subrow;      // 0..127
        int rr = (r < Mblk) ? r : 0;
        size_t srow = expert_mode ? (size_t)row_tok[rowbeg + mtile + rr]
                                  : (size_t)(rowbeg + mtile + rr);
        aptr[c] = A + srow * (size_t)K + lseg * 8;
    }
    // B: 8 chunks each; 2 per wave per matrix
    const f16 *b1ptr[2], *b3ptr[2];
    #pragma unroll
    for (int c = 0; c < 2; ++c) {
        int r = (wave * 2 + c) * 8 + subrow;      // 0..63
        b1ptr[c] = W1e + (size_t)(n0 + r) * K + lseg * 8;
        b3ptr[c] = W3e + (size_t)(n0 + r) * K + lseg * 8;
    }

    int lrow = lane & 15, lquad = lane >> 4;
    int wm = (wave & 1) * 64, wn = (wave >> 1) * 32;

    f32x4 accg[4][2], accu[4][2];
    #pragma unroll
    for (int i = 0; i < 4; ++i)
        #pragma unroll
        for (int j = 0; j < 2; ++j) {
            f32x4 z = {0.f, 0.f, 0.f, 0.f};
            accg[i][j] = z; accu[i][j] = z;
        }

    for (int k0 = 0; k0 < K; k0 += 64) {
        #pragma unroll
        for (int c = 0; c < 4; ++c)
            gl2lds16(aptr[c] + k0, &sA[(wave * 4 + c) * 512]);
        #pragma unroll
        for (int c = 0; c < 2; ++c) {
            gl2lds16(b1ptr[c] + k0, &sB1[(wave * 2 + c) * 512]);
            gl2lds16(b3ptr[c] + k0, &sB3[(wave * 2 + c) * 512]);
        }
        __syncthreads();
        #pragma unroll
        for (int ks = 0; ks < 2; ++ks) {
            int seg = ks * 4 + lquad;             // logical 16B seg 0..7
            f16x8 a[4], b1[2], b3[2];
            #pragma unroll
            for (int i = 0; i < 4; ++i) a[i] = FRAG(sA, wm + i * 16 + lrow, seg);
            #pragma unroll
            for (int j = 0; j < 2; ++j) {
                b1[j] = FRAG(sB1, wn + j * 16 + lrow, seg);
                b3[j] = FRAG(sB3, wn + j * 16 + lrow, seg);
            }
            #pragma unroll
            for (int i = 0; i < 4; ++i)
                #pragma unroll
                for (int j = 0; j < 2; ++j) {
                    accg[i][j] = __builtin_amdgcn_mfma_f32_16x16x32_f16(a[i], b1[j], accg[i][j], 0, 0, 0);
                    accu[i][j] = __builtin_amdgcn_mfma_f32_16x16x32_f16(a[i], b3[j], accu[i][j], 0, 0, 0);
                }
        }
        __syncthreads();
    }

    f16* Hrow = Hout + (size_t)(rowbeg + mtile) * Nld + n0;
    #pragma unroll
    for (int i = 0; i < 4; ++i)
        #pragma unroll
        for (int j = 0; j < 2; ++j)
            #pragma unroll
            for (int r = 0; r < 4; ++r) {
                int m = wm + i * 16 + lquad * 4 + r;
                if (m < Mblk) {
                    int n = wn + j * 16 + lrow;
                    float g = accg[i][j][r], u = accu[i][j][r];
                    float h = g / (1.f + __expf(-g)) * u;
                    Hrow[(size_t)m * Nld + n] = (f16)h;
                }
            }
}

// ---------------------------------------------------------------------------
// Down GEMM (all-f16): Y = A.W^T.  Tile 128x128.
// ---------------------------------------------------------------------------
__global__ __launch_bounds__(256, 2) void k_down(
    const f16* __restrict__ A, const f16* __restrict__ W,
    f16* __restrict__ Y,
    const int* __restrict__ offsets, const int* __restrict__ counts,
    int K, int Nld, int Mtot, int expert_mode)
{
    int e = expert_mode ? blockIdx.z : 0;
    int rowbeg = expert_mode ? offsets[e] : 0;
    int M = expert_mode ? (counts[e] < CAPC ? counts[e] : CAPC) : Mtot;
    int mtile = blockIdx.y * 128;
    if (mtile >= M) return;
    int Mblk = M - mtile; if (Mblk > 128) Mblk = 128;
    int n0 = blockIdx.x * 128;
    const f16* We = W + (size_t)e * Nld * K;

    __shared__ __align__(16) f16 sA[128 * 64];
    __shared__ __align__(16) f16 sW[128 * 64];

    int tid = threadIdx.x, wave = tid >> 6, lane = tid & 63;
    int subrow = lane >> 3;
    int lseg = (lane & 7) ^ subrow;

    const f16 *aptr[4], *wptr[4];
    #pragma unroll
    for (int c = 0; c < 4; ++c) {
        int r = (wave * 4 + c) * 8 + subrow;      // 0..127
        int rr = (r < Mblk) ? r : 0;
        aptr[c] = A + (size_t)(rowbeg + mtile + rr) * K + lseg * 8;
        wptr[c] = We + (size_t)(n0 + r) * K + lseg * 8;
    }

    int lrow = lane & 15, lquad = lane >> 4;
    int wm = (wave & 1) * 64, wn = (wave >> 1) * 64;

    f32x4 acc[4][4];
    #pragma unroll
    for (int i = 0; i < 4; ++i)
        #pragma unroll
        for (int j = 0; j < 4; ++j) { f32x4 z = {0.f, 0.f, 0.f, 0.f}; acc[i][j] = z; }

    for (int k0 = 0; k0 < K; k0 += 64) {
        #pragma unroll
        for (int c = 0; c < 4; ++c) {
            gl2lds16(aptr[c] + k0, &sA[(wave * 4 + c) * 512]);
            gl2lds16(wptr[c] + k0, &sW[(wave * 4 + c) * 512]);
        }
        __syncthreads();
        #pragma unroll
        for (int ks = 0; ks < 2; ++ks) {
            int seg = ks * 4 + lquad;
            f16x8 a[4], b[4];
            #pragma unroll
            for (int i = 0; i < 4; ++i) a[i] = FRAG(sA, wm + i * 16 + lrow, seg);
            #pragma unroll
            for (int j = 0; j < 4; ++j) b[j] = FRAG(sW, wn + j * 16 + lrow, seg);
            #pragma unroll
            for (int i = 0; i < 4; ++i)
                #pragma unroll
                for (int j = 0; j < 4; ++j)
                    acc[i][j] = __builtin_amdgcn_mfma_f32_16x16x32_f16(a[i], b[j], acc[i][j], 0, 0, 0);
        }
        __syncthreads();
    }

    f16* Yrow = Y + (size_t)(rowbeg + mtile) * Nld + n0;
    #pragma unroll
    for (int i = 0; i < 4; ++i)
        #pragma unroll
        for (int j = 0; j < 4; ++j)
            #pragma unroll
            for (int r = 0; r < 4; ++r) {
                int m = wm + i * 16 + lquad * 4 + r;
                if (m < Mblk)
                    Yrow[(size_t)m * Nld + wn + j * 16 + lrow] = (f16)acc[i][j][r];
            }
}

// ---------------------------------------------------------------------------
// Combine: out[t] = ys[t] + sum_k w_k * y[row(t,k)]
// ---------------------------------------------------------------------------
__global__ void k_combine(const f16* __restrict__ y, const f16* __restrict__ ys,
                          const int* __restrict__ slot_e, const int* __restrict__ slot_pos,
                          const float* __restrict__ slot_w, const int* __restrict__ offsets,
                          float* __restrict__ out)
{
    int t = blockIdx.x, i = threadIdx.x;
    size_t col = (size_t)i * 4;
    f16x4 s = *(const f16x4*)(ys + (size_t)t * HDIM + col);
    float a0 = (float)s[0], a1 = (float)s[1], a2 = (float)s[2], a3 = (float)s[3];
    #pragma unroll
    for (int k = 0; k < TOPK; ++k) {
        int sidx = t * TOPK + k;
        int p = slot_pos[sidx];
        if (p < CAPC) {
            int row = offsets[slot_e[sidx]] + p;
            float w = slot_w[sidx];
            f16x4 v = *(const f16x4*)(y + (size_t)row * HDIM + col);
            a0 += w * (float)v[0]; a1 += w * (float)v[1];
            a2 += w * (float)v[2]; a3 += w * (float)v[3];
        }
    }
    float4 o = {a0, a1, a2, a3};
    *(float4*)(out + (size_t)t * HDIM + col) = o;
}

extern "C" void kernel_launch(void* const* d_in, const int* in_sizes, int n_in,
                              void* d_out, int out_size, void* d_ws, size_t ws_size,
                              hipStream_t stream)
{
    const float* x  = (const float*)d_in[0];
    const float* gw = (const float*)d_in[1];
    const float* eb = (const float*)d_in[2];
    const float* w1 = (const float*)d_in[3];
    const float* w2 = (const float*)d_in[4];
    const float* w3 = (const float*)d_in[5];
    const float* sg = (const float*)d_in[6];
    const float* su = (const float*)d_in[7];
    const float* sd = (const float*)d_in[8];
    float* out = (float*)d_out;

    char* p = (char*)d_ws;
    size_t off = 0;
    auto alloc = [&](size_t n) { void* r = p + off; off = (off + n + 255) & ~(size_t)255; return r; };
    int*   counts   = (int*)alloc(NEXP * 4);
    int*   offsets  = (int*)alloc(NEXP * 4);
    int*   slot_e   = (int*)alloc((size_t)T_TOK * TOPK * 4);
    int*   slot_pos = (int*)alloc((size_t)T_TOK * TOPK * 4);
    float* slot_w   = (float*)alloc((size_t)T_TOK * TOPK * 4);
    int*   row_tok  = (int*)alloc((size_t)T_TOK * TOPK * 4);
    f16*   xb  = (f16*)alloc((size_t)T_TOK * HDIM * 2);                 // 4 MB
    f16*   h   = (f16*)alloc((size_t)T_TOK * TOPK * FDIM * 2);          // 16 MB
    f16*   y   = (f16*)alloc((size_t)T_TOK * TOPK * HDIM * 2);          // 32 MB
    f16*   hs  = (f16*)alloc((size_t)T_TOK * 2 * FDIM * 2);             // 4 MB
    f16*   ys  = (f16*)alloc((size_t)T_TOK * HDIM * 2);                 // 4 MB
    f16*   wbufA = (f16*)alloc((size_t)NEXP * FDIM * HDIM * 2);         // 67 MB (w1h, then w2h)
    f16*   wbufB = (f16*)alloc((size_t)NEXP * FDIM * HDIM * 2);         // 67 MB (w3h)
    f16*   sgh = (f16*)alloc((size_t)2 * FDIM * HDIM * 2);              // 2 MB
    f16*   suh = (f16*)alloc((size_t)2 * FDIM * HDIM * 2);              // 2 MB
    f16*   sdh = (f16*)alloc((size_t)HDIM * 2 * FDIM * 2);              // 2 MB

    hipMemsetAsync(counts, 0, NEXP * 4, stream);
    k_route<<<T_TOK, 64, 0, stream>>>(x, gw, eb, xb, counts, slot_e, slot_pos, slot_w);
    k_scan<<<1, 64, 0, stream>>>(counts, offsets);
    k_rowmap<<<(T_TOK * TOPK + 255) / 256, 256, 0, stream>>>(slot_e, slot_pos, offsets, row_tok);

    // weight conversion fp32 -> f16
    const int EW8 = NEXP * FDIM * HDIM / 8;      // 4194304
    const int SW8 = 2 * FDIM * HDIM / 8;         // 131072
    k_cvt<<<(EW8 + 255) / 256, 256, 0, stream>>>(w1, wbufA, EW8);
    k_cvt<<<(EW8 + 255) / 256, 256, 0, stream>>>(w3, wbufB, EW8);
    k_cvt<<<(SW8 + 255) / 256, 256, 0, stream>>>(sg, sgh, SW8);
    k_cvt<<<(SW8 + 255) / 256, 256, 0, stream>>>(su, suh, SW8);
    k_cvt<<<(SW8 + 255) / 256, 256, 0, stream>>>(sd, sdh, SW8);

    // gate-up GEMMs
    k_gateup<<<dim3(FDIM / 64, CAPC / 128, NEXP), 256, 0, stream>>>(
        xb, wbufA, wbufB, h, offsets, counts, row_tok, HDIM, FDIM, 0, 1);
    k_gateup<<<dim3((2 * FDIM) / 64, T_TOK / 128, 1), 256, 0, stream>>>(
        xb, sgh, suh, hs, offsets, counts, row_tok, HDIM, 2 * FDIM, T_TOK, 0);

    // w2 conversion reuses wbufA (gate-up done with it, stream-ordered)
    k_cvt<<<(EW8 + 255) / 256, 256, 0, stream>>>(w2, wbufA, EW8);

    // down GEMMs
    k_down<<<dim3(HDIM / 128, CAPC / 128, NEXP), 256, 0, stream>>>(
        h, wbufA, y, offsets, counts, FDIM, HDIM, 0, 1);
    k_down<<<dim3(HDIM / 128, T_TOK / 128, 1), 256, 0, stream>>>(
        hs, sdh, ys, offsets, counts, 2 * FDIM, HDIM, T_TOK, 0);

    k_combine<<<T_TOK, 256, 0, stream>>>(y, ys, slot_e, slot_pos, slot_w, offsets, out);
}

// Round 3
// 692.428 us; speedup vs baseline: 1.3116x; 1.0547x over previous
//
#include <hip/hip_runtime.h>

#define T_TOK 2048
#define HDIM  1024
#define FDIM  512
#define NEXP  64
#define TOPK  8
#define NGRP  8
#define TGRP  4
#define CAPC  1024
#define SCALE_F 2.5f

typedef _Float16 f16;
typedef _Float16 f16x4 __attribute__((ext_vector_type(4)));
typedef _Float16 f16x8 __attribute__((ext_vector_type(8)));
typedef float    f32x4 __attribute__((ext_vector_type(4)));

typedef const __attribute__((address_space(1))) void* gas_t;
typedef __attribute__((address_space(3))) void* las_t;
__device__ __forceinline__ void gl2lds16(const void* g, void* l) {
    __builtin_amdgcn_global_load_lds((gas_t)g, (las_t)l, 16, 0, 0);
}
// XOR-swizzled fragment read: logical (row r, 16B-seg s) -> phys seg s^(r&7)
#define FRAG(S, r, s) (*(const f16x8*)&S[(r)*64 + (((s) ^ ((r)&7)))*8])

// ---------------------------------------------------------------------------
// fp32 -> f16 streaming conversion (8 elems/thread)
// ---------------------------------------------------------------------------
__global__ void k_cvt(const float* __restrict__ src, f16* __restrict__ dst, int n8)
{
    int i = blockIdx.x * blockDim.x + threadIdx.x;
    if (i >= n8) return;
    const float4* s = (const float4*)src + (size_t)i * 2;
    float4 a = s[0], b = s[1];
    f16x8 h = { (f16)a.x, (f16)a.y, (f16)a.z, (f16)a.w,
                (f16)b.x, (f16)b.y, (f16)b.z, (f16)b.w };
    *(f16x8*)(dst + (size_t)i * 8) = h;
}

// ---------------------------------------------------------------------------
// Logits GEMM (fp32): logits[T,64] = x[T,H] . gw[64,H]^T
// Block: 256 thr, 8 tokens. thread -> (t=tid&7, experts tid>>3 and +32).
// All compute LDS reads are broadcast-or-distinct-bank by construction.
// ---------------------------------------------------------------------------
__global__ __launch_bounds__(256) void k_logits(const float* __restrict__ x,
                                                const float* __restrict__ gw,
                                                float* __restrict__ logits)
{
    __shared__ float sX[8][132];     // stride 132 floats = 528 B (16B-aligned)
    __shared__ float sGW[64][132];
    int tid = threadIdx.x;
    int t0 = blockIdx.x * 8;
    int tl = tid & 7;
    int eb = tid >> 3;               // 0..31
    f32x4 acc0 = {0.f,0.f,0.f,0.f}, acc1 = {0.f,0.f,0.f,0.f};

    for (int hc0 = 0; hc0 < HDIM; hc0 += 128) {
        __syncthreads();
        {   // stage x chunk: 8 rows x 128 floats
            int row = tid >> 5, c4 = tid & 31;
            float4 v = *(const float4*)(x + (size_t)(t0 + row) * HDIM + hc0 + c4 * 4);
            *(float4*)&sX[row][c4 * 4] = v;
        }
        #pragma unroll
        for (int k = 0; k < 8; ++k) {   // stage gw chunk: 64 rows x 128
            int row = k * 8 + (tid >> 5), c4 = tid & 31;
            float4 v = *(const float4*)(gw + (size_t)row * HDIM + hc0 + c4 * 4);
            *(float4*)&sGW[row][c4 * 4] = v;
        }
        __syncthreads();
        #pragma unroll
        for (int c4 = 0; c4 < 32; ++c4) {
            float4 ax = *(const float4*)&sX[tl][c4 * 4];
            float4 g0 = *(const float4*)&sGW[eb][c4 * 4];
            float4 g1 = *(const float4*)&sGW[eb + 32][c4 * 4];
            acc0.x += ax.x * g0.x; acc0.y += ax.y * g0.y;
            acc0.z += ax.z * g0.z; acc0.w += ax.w * g0.w;
            acc1.x += ax.x * g1.x; acc1.y += ax.y * g1.y;
            acc1.z += ax.z * g1.z; acc1.w += ax.w * g1.w;
        }
    }
    float l0 = (acc0.x + acc0.y) + (acc0.z + acc0.w);
    float l1 = (acc1.x + acc1.y) + (acc1.z + acc1.w);
    logits[(size_t)(t0 + tl) * NEXP + eb]      = l0;
    logits[(size_t)(t0 + tl) * NEXP + eb + 32] = l1;
}

// ---------------------------------------------------------------------------
// Top-k per token: one wave, logits read coalesced, group-limited top-8.
// ---------------------------------------------------------------------------
__global__ void k_topk(const float* __restrict__ logits, const float* __restrict__ ebias,
                       int* __restrict__ counts,
                       int* __restrict__ slot_e, int* __restrict__ slot_pos,
                       float* __restrict__ slot_w)
{
    int t = blockIdx.x;
    int lane = threadIdx.x; // 64 = 1 wave
    __shared__ float sS[NEXP], sF[NEXP];
    __shared__ float gsc[NGRP];
    __shared__ unsigned gmask_s;
    __shared__ int sIdx[TOPK];

    float logit = logits[(size_t)t * NEXP + lane];
    float score = 1.f / (1.f + __expf(-logit));
    float sfc = score + ebias[lane];
    sS[lane] = score; sF[lane] = sfc;
    __syncthreads();

    if (lane < NGRP) {
        float m1 = -1e30f, m2 = -1e30f;
        for (int j = 0; j < NEXP / NGRP; ++j) {
            float v = sF[lane * (NEXP / NGRP) + j];
            if (v > m1) { m2 = m1; m1 = v; } else if (v > m2) m2 = v;
        }
        gsc[lane] = m1 + m2;
    }
    __syncthreads();
    if (lane == 0) {
        unsigned gm = 0;
        for (int s = 0; s < TGRP; ++s) {
            float best = -1e30f; int bg = 0;
            for (int g = 0; g < NGRP; ++g)
                if (!((gm >> g) & 1) && gsc[g] > best) { best = gsc[g]; bg = g; }
            gm |= 1u << bg;
        }
        gmask_s = gm;
    }
    __syncthreads();

    float vv = ((gmask_s >> (lane >> 3)) & 1) ? sfc : 0.0f;
    for (int k = 0; k < TOPK; ++k) {
        float bv = vv; int bi = lane;
        for (int off = 32; off; off >>= 1) {
            float ov = __shfl_down(bv, off);
            int   oi = __shfl_down(bi, off);
            if (ov > bv || (ov == bv && oi < bi)) { bv = ov; bi = oi; }
        }
        bi = __shfl(bi, 0);
        if (lane == bi) vv = -1e30f;
        if (lane == 0) sIdx[k] = bi;
    }
    __syncthreads();
    if (lane == 0) {
        float sum = 0.f;
        for (int k = 0; k < TOPK; ++k) sum += sS[sIdx[k]];
        float inv = SCALE_F / (sum + 1e-20f);
        for (int k = 0; k < TOPK; ++k) {
            int e = sIdx[k];
            int pos = atomicAdd(&counts[e], 1);
            int s = t * TOPK + k;
            slot_e[s] = e; slot_pos[s] = pos; slot_w[s] = sS[e] * inv;
        }
    }
}

__global__ void k_scan(const int* __restrict__ counts, int* __restrict__ offsets)
{
    if (threadIdx.x == 0) {
        int s = 0;
        for (int e = 0; e < NEXP; ++e) { offsets[e] = s; s += counts[e]; }
    }
}

__global__ void k_rowmap(const int* __restrict__ slot_e, const int* __restrict__ slot_pos,
                         const int* __restrict__ offsets, int* __restrict__ row_tok)
{
    int s = blockIdx.x * 256 + threadIdx.x;
    if (s >= T_TOK * TOPK) return;
    int p = slot_pos[s];
    if (p >= CAPC) return;
    row_tok[offsets[slot_e[s]] + p] = s >> 3;
}

// ---------------------------------------------------------------------------
// Fused gate-up GEMM (all-f16): H = silu(A.W1^T) * (A.W3^T).
// Tile 128M x 64N; global_load_lds(16B) staging, XOR-swizzled LDS.
// ---------------------------------------------------------------------------
__global__ __launch_bounds__(256, 2) void k_gateup(
    const f16* __restrict__ A, const f16* __restrict__ W1,
    const f16* __restrict__ W3, f16* __restrict__ Hout,
    const int* __restrict__ offsets, const int* __restrict__ counts,
    const int* __restrict__ row_tok,
    int K, int Nld, int Mtot, int expert_mode)
{
    int e = expert_mode ? blockIdx.z : 0;
    int rowbeg = expert_mode ? offsets[e] : 0;
    int M = expert_mode ? (counts[e] < CAPC ? counts[e] : CAPC) : Mtot;
    int mtile = blockIdx.y * 128;
    if (mtile >= M) return;
    int Mblk = M - mtile; if (Mblk > 128) Mblk = 128;
    int n0 = blockIdx.x * 64;
    const f16* W1e = W1 + (size_t)e * Nld * K;
    const f16* W3e = W3 + (size_t)e * Nld * K;

    __shared__ __align__(16) f16 sA[128 * 64];
    __shared__ __align__(16) f16 sB1[64 * 64];
    __shared__ __align__(16) f16 sB3[64 * 64];

    int tid = threadIdx.x, wave = tid >> 6, lane = tid & 63;
    int subrow = lane >> 3;
    int lseg = (lane & 7) ^ subrow;

    const f16* aptr[4];
    #pragma unroll
    for (int c = 0; c < 4; ++c) {
        int r = (wave * 4 + c) * 8 + subrow;
        int rr = (r < Mblk) ? r : 0;
        size_t srow = expert_mode ? (size_t)row_tok[rowbeg + mtile + rr]
                                  : (size_t)(rowbeg + mtile + rr);
        aptr[c] = A + srow * (size_t)K + lseg * 8;
    }
    const f16 *b1ptr[2], *b3ptr[2];
    #pragma unroll
    for (int c = 0; c < 2; ++c) {
        int r = (wave * 2 + c) * 8 + subrow;
        b1ptr[c] = W1e + (size_t)(n0 + r) * K + lseg * 8;
        b3ptr[c] = W3e + (size_t)(n0 + r) * K + lseg * 8;
    }

    int lrow = lane & 15, lquad = lane >> 4;
    int wm = (wave & 1) * 64, wn = (wave >> 1) * 32;

    f32x4 accg[4][2], accu[4][2];
    #pragma unroll
    for (int i = 0; i < 4; ++i)
        #pragma unroll
        for (int j = 0; j < 2; ++j) {
            f32x4 z = {0.f, 0.f, 0.f, 0.f};
            accg[i][j] = z; accu[i][j] = z;
        }

    for (int k0 = 0; k0 < K; k0 += 64) {
        #pragma unroll
        for (int c = 0; c < 4; ++c)
            gl2lds16(aptr[c] + k0, &sA[(wave * 4 + c) * 512]);
        #pragma unroll
        for (int c = 0; c < 2; ++c) {
            gl2lds16(b1ptr[c] + k0, &sB1[(wave * 2 + c) * 512]);
            gl2lds16(b3ptr[c] + k0, &sB3[(wave * 2 + c) * 512]);
        }
        __syncthreads();
        #pragma unroll
        for (int ks = 0; ks < 2; ++ks) {
            int seg = ks * 4 + lquad;
            f16x8 a[4], b1[2], b3[2];
            #pragma unroll
            for (int i = 0; i < 4; ++i) a[i] = FRAG(sA, wm + i * 16 + lrow, seg);
            #pragma unroll
            for (int j = 0; j < 2; ++j) {
                b1[j] = FRAG(sB1, wn + j * 16 + lrow, seg);
                b3[j] = FRAG(sB3, wn + j * 16 + lrow, seg);
            }
            #pragma unroll
            for (int i = 0; i < 4; ++i)
                #pragma unroll
                for (int j = 0; j < 2; ++j) {
                    accg[i][j] = __builtin_amdgcn_mfma_f32_16x16x32_f16(a[i], b1[j], accg[i][j], 0, 0, 0);
                    accu[i][j] = __builtin_amdgcn_mfma_f32_16x16x32_f16(a[i], b3[j], accu[i][j], 0, 0, 0);
                }
        }
        __syncthreads();
    }

    f16* Hrow = Hout + (size_t)(rowbeg + mtile) * Nld + n0;
    #pragma unroll
    for (int i = 0; i < 4; ++i)
        #pragma unroll
        for (int j = 0; j < 2; ++j)
            #pragma unroll
            for (int r = 0; r < 4; ++r) {
                int m = wm + i * 16 + lquad * 4 + r;
                if (m < Mblk) {
                    int n = wn + j * 16 + lrow;
                    float g = accg[i][j][r], u = accu[i][j][r];
                    float h = g / (1.f + __expf(-g)) * u;
                    Hrow[(size_t)m * Nld + n] = (f16)h;
                }
            }
}

// ---------------------------------------------------------------------------
// Down GEMM (all-f16): Y = A.W^T.  Tile 128x128.
// ---------------------------------------------------------------------------
__global__ __launch_bounds__(256, 2) void k_down(
    const f16* __restrict__ A, const f16* __restrict__ W,
    f16* __restrict__ Y,
    const int* __restrict__ offsets, const int* __restrict__ counts,
    int K, int Nld, int Mtot, int expert_mode)
{
    int e = expert_mode ? blockIdx.z : 0;
    int rowbeg = expert_mode ? offsets[e] : 0;
    int M = expert_mode ? (counts[e] < CAPC ? counts[e] : CAPC) : Mtot;
    int mtile = blockIdx.y * 128;
    if (mtile >= M) return;
    int Mblk = M - mtile; if (Mblk > 128) Mblk = 128;
    int n0 = blockIdx.x * 128;
    const f16* We = W + (size_t)e * Nld * K;

    __shared__ __align__(16) f16 sA[128 * 64];
    __shared__ __align__(16) f16 sW[128 * 64];

    int tid = threadIdx.x, wave = tid >> 6, lane = tid & 63;
    int subrow = lane >> 3;
    int lseg = (lane & 7) ^ subrow;

    const f16 *aptr[4], *wptr[4];
    #pragma unroll
    for (int c = 0; c < 4; ++c) {
        int r = (wave * 4 + c) * 8 + subrow;
        int rr = (r < Mblk) ? r : 0;
        aptr[c] = A + (size_t)(rowbeg + mtile + rr) * K + lseg * 8;
        wptr[c] = We + (size_t)(n0 + r) * K + lseg * 8;
    }

    int lrow = lane & 15, lquad = lane >> 4;
    int wm = (wave & 1) * 64, wn = (wave >> 1) * 64;

    f32x4 acc[4][4];
    #pragma unroll
    for (int i = 0; i < 4; ++i)
        #pragma unroll
        for (int j = 0; j < 4; ++j) { f32x4 z = {0.f, 0.f, 0.f, 0.f}; acc[i][j] = z; }

    for (int k0 = 0; k0 < K; k0 += 64) {
        #pragma unroll
        for (int c = 0; c < 4; ++c) {
            gl2lds16(aptr[c] + k0, &sA[(wave * 4 + c) * 512]);
            gl2lds16(wptr[c] + k0, &sW[(wave * 4 + c) * 512]);
        }
        __syncthreads();
        #pragma unroll
        for (int ks = 0; ks < 2; ++ks) {
            int seg = ks * 4 + lquad;
            f16x8 a[4], b[4];
            #pragma unroll
            for (int i = 0; i < 4; ++i) a[i] = FRAG(sA, wm + i * 16 + lrow, seg);
            #pragma unroll
            for (int j = 0; j < 4; ++j) b[j] = FRAG(sW, wn + j * 16 + lrow, seg);
            #pragma unroll
            for (int i = 0; i < 4; ++i)
                #pragma unroll
                for (int j = 0; j < 4; ++j)
                    acc[i][j] = __builtin_amdgcn_mfma_f32_16x16x32_f16(a[i], b[j], acc[i][j], 0, 0, 0);
        }
        __syncthreads();
    }

    f16* Yrow = Y + (size_t)(rowbeg + mtile) * Nld + n0;
    #pragma unroll
    for (int i = 0; i < 4; ++i)
        #pragma unroll
        for (int j = 0; j < 4; ++j)
            #pragma unroll
            for (int r = 0; r < 4; ++r) {
                int m = wm + i * 16 + lquad * 4 + r;
                if (m < Mblk)
                    Yrow[(size_t)m * Nld + wn + j * 16 + lrow] = (f16)acc[i][j][r];
            }
}

// ---------------------------------------------------------------------------
// Combine: out[t] = ys[t] + sum_k w_k * y[row(t,k)]
// ---------------------------------------------------------------------------
__global__ void k_combine(const f16* __restrict__ y, const f16* __restrict__ ys,
                          const int* __restrict__ slot_e, const int* __restrict__ slot_pos,
                          const float* __restrict__ slot_w, const int* __restrict__ offsets,
                          float* __restrict__ out)
{
    int t = blockIdx.x, i = threadIdx.x;
    size_t col = (size_t)i * 4;
    f16x4 s = *(const f16x4*)(ys + (size_t)t * HDIM + col);
    float a0 = (float)s[0], a1 = (float)s[1], a2 = (float)s[2], a3 = (float)s[3];
    #pragma unroll
    for (int k = 0; k < TOPK; ++k) {
        int sidx = t * TOPK + k;
        int p = slot_pos[sidx];
        if (p < CAPC) {
            int row = offsets[slot_e[sidx]] + p;
            float w = slot_w[sidx];
            f16x4 v = *(const f16x4*)(y + (size_t)row * HDIM + col);
            a0 += w * (float)v[0]; a1 += w * (float)v[1];
            a2 += w * (float)v[2]; a3 += w * (float)v[3];
        }
    }
    float4 o = {a0, a1, a2, a3};
    *(float4*)(out + (size_t)t * HDIM + col) = o;
}

extern "C" void kernel_launch(void* const* d_in, const int* in_sizes, int n_in,
                              void* d_out, int out_size, void* d_ws, size_t ws_size,
                              hipStream_t stream)
{
    const float* x  = (const float*)d_in[0];
    const float* gw = (const float*)d_in[1];
    const float* eb = (const float*)d_in[2];
    const float* w1 = (const float*)d_in[3];
    const float* w2 = (const float*)d_in[4];
    const float* w3 = (const float*)d_in[5];
    const float* sg = (const float*)d_in[6];
    const float* su = (const float*)d_in[7];
    const float* sd = (const float*)d_in[8];
    float* out = (float*)d_out;

    char* p = (char*)d_ws;
    size_t off = 0;
    auto alloc = [&](size_t n) { void* r = p + off; off = (off + n + 255) & ~(size_t)255; return r; };
    int*   counts   = (int*)alloc(NEXP * 4);
    int*   offsets  = (int*)alloc(NEXP * 4);
    int*   slot_e   = (int*)alloc((size_t)T_TOK * TOPK * 4);
    int*   slot_pos = (int*)alloc((size_t)T_TOK * TOPK * 4);
    float* slot_w   = (float*)alloc((size_t)T_TOK * TOPK * 4);
    int*   row_tok  = (int*)alloc((size_t)T_TOK * TOPK * 4);
    float* logits   = (float*)alloc((size_t)T_TOK * NEXP * 4);          // 512 KB
    f16*   xb  = (f16*)alloc((size_t)T_TOK * HDIM * 2);                 // 4 MB
    f16*   h   = (f16*)alloc((size_t)T_TOK * TOPK * FDIM * 2);          // 16 MB
    f16*   y   = (f16*)alloc((size_t)T_TOK * TOPK * HDIM * 2);          // 32 MB
    f16*   hs  = (f16*)alloc((size_t)T_TOK * 2 * FDIM * 2);             // 4 MB
    f16*   ys  = (f16*)alloc((size_t)T_TOK * HDIM * 2);                 // 4 MB
    f16*   wbufA = (f16*)alloc((size_t)NEXP * FDIM * HDIM * 2);         // 67 MB (w1h, then w2h)
    f16*   wbufB = (f16*)alloc((size_t)NEXP * FDIM * HDIM * 2);         // 67 MB (w3h)
    f16*   sgh = (f16*)alloc((size_t)2 * FDIM * HDIM * 2);              // 2 MB
    f16*   suh = (f16*)alloc((size_t)2 * FDIM * HDIM * 2);              // 2 MB
    f16*   sdh = (f16*)alloc((size_t)HDIM * 2 * FDIM * 2);              // 2 MB

    hipMemsetAsync(counts, 0, NEXP * 4, stream);

    // routing path
    const int XW8 = T_TOK * HDIM / 8;            // 262144
    k_cvt<<<(XW8 + 255) / 256, 256, 0, stream>>>(x, xb, XW8);
    k_logits<<<T_TOK / 8, 256, 0, stream>>>(x, gw, logits);
    k_topk<<<T_TOK, 64, 0, stream>>>(logits, eb, counts, slot_e, slot_pos, slot_w);
    k_scan<<<1, 64, 0, stream>>>(counts, offsets);
    k_rowmap<<<(T_TOK * TOPK + 255) / 256, 256, 0, stream>>>(slot_e, slot_pos, offsets, row_tok);

    // weight conversion fp32 -> f16
    const int EW8 = NEXP * FDIM * HDIM / 8;      // 4194304
    const int SW8 = 2 * FDIM * HDIM / 8;         // 131072
    k_cvt<<<(EW8 + 255) / 256, 256, 0, stream>>>(w1, wbufA, EW8);
    k_cvt<<<(EW8 + 255) / 256, 256, 0, stream>>>(w3, wbufB, EW8);
    k_cvt<<<(SW8 + 255) / 256, 256, 0, stream>>>(sg, sgh, SW8);
    k_cvt<<<(SW8 + 255) / 256, 256, 0, stream>>>(su, suh, SW8);
    k_cvt<<<(SW8 + 255) / 256, 256, 0, stream>>>(sd, sdh, SW8);

    // gate-up GEMMs
    k_gateup<<<dim3(FDIM / 64, CAPC / 128, NEXP), 256, 0, stream>>>(
        xb, wbufA, wbufB, h, offsets, counts, row_tok, HDIM, FDIM, 0, 1);
    k_gateup<<<dim3((2 * FDIM) / 64, T_TOK / 128, 1), 256, 0, stream>>>(
        xb, sgh, suh, hs, offsets, counts, row_tok, HDIM, 2 * FDIM, T_TOK, 0);

    // w2 conversion reuses wbufA (gate-up done with it, stream-ordered)
    k_cvt<<<(EW8 + 255) / 256, 256, 0, stream>>>(w2, wbufA, EW8);

    // down GEMMs
    k_down<<<dim3(HDIM / 128, CAPC / 128, NEXP), 256, 0, stream>>>(
        h, wbufA, y, offsets, counts, FDIM, HDIM, 0, 1);
    k_down<<<dim3(HDIM / 128, T_TOK / 128, 1), 256, 0, stream>>>(
        hs, sdh, ys, offsets, counts, 2 * FDIM, HDIM, T_TOK, 0);

    k_combine<<<T_TOK, 256, 0, stream>>>(y, ys, slot_e, slot_pos, slot_w, offsets, out);
}